// Round 1
// baseline (294.473 us; speedup 1.0000x reference)
//
#include <hip/hip_runtime.h>
#include <hip/hip_bf16.h>

typedef float    f4v    __attribute__((ext_vector_type(4)));
typedef short    short8 __attribute__((ext_vector_type(8)));
typedef unsigned u2v    __attribute__((ext_vector_type(2)));

constexpr int Bn = 4096, TR = 16;

// ---- split-bf16 helpers ----------------------------------------------------
__device__ inline unsigned cvt2(float x, float y) {
  union { __hip_bfloat162 h; unsigned u; } c;
  c.h = __float22bfloat162_rn(float2{x, y});
  return c.u;   // low16 = bf16(x), high16 = bf16(y)
}
__device__ inline void split_pair(float x, float y, unsigned& hp, unsigned& lp) {
  hp = cvt2(x, y);
  float hx = __uint_as_float(hp << 16);
  float hy = __uint_as_float(hp & 0xffff0000u);
  lp = cvt2(x - hx, y - hy);
}
union S8U { unsigned u[4]; short8 s; };
__device__ inline void split8(const float v[8], short8& hi, short8& lo) {
  S8U h, l;
  #pragma unroll
  for (int d = 0; d < 4; ++d) split_pair(v[2 * d], v[2 * d + 1], h.u[d], l.u[d]);
  hi = h.s; lo = l.s;
}
__device__ inline void split8p(const float* p, short8& hi, short8& lo) {
  f4v a = *(const f4v*)p, b = *(const f4v*)(p + 4);
  float v[8] = {a[0], a[1], a[2], a[3], b[0], b[1], b[2], b[3]};
  split8(v, hi, lo);
}
__device__ inline f4v mfma16(short8 a, short8 b, f4v c) {
  return __builtin_amdgcn_mfma_f32_16x16x32_bf16(a, b, c, 0, 0, 0);
}
__device__ __attribute__((always_inline)) inline f4v gdot8(
    const short8 (&ah)[8], const short8 (&al)[8],
    const short8 (&bh)[8], const short8 (&bl)[8]) {
  f4v c = {0.f, 0.f, 0.f, 0.f};
  #pragma unroll
  for (int s = 0; s < 8; ++s) {
    c = mfma16(ah[s], bh[s], c);
    c = mfma16(al[s], bh[s], c);
    c = mfma16(ah[s], bl[s], c);
  }
  return c;
}

// pack 4 fp32 -> bf16 hi/lo fragment words, write hi at dst[0..1], lo at dst[256..257]
__device__ inline void pack_write(unsigned* dst, float z0, float z1, float z2, float z3) {
  unsigned a0, b0, a1, b1;
  split_pair(z0, z1, a0, b0);
  split_pair(z2, z3, a1, b1);
  u2v hv; hv[0] = a0; hv[1] = a1;
  u2v lv; lv[0] = b0; lv[1] = b1;
  *(u2v*)&dst[0]   = hv;
  *(u2v*)&dst[256] = lv;
}

// ---------------------------------------------------------------------------
// k_prep: KAT[n][m] = (inv(A A^T + 1e-6 I) @ A)^T -> ws. 1 block, 256 thr.
// ---------------------------------------------------------------------------
__global__ __launch_bounds__(256) void k_prep(const float* __restrict__ A,
                                              float* __restrict__ KAT) {
  __shared__ __align__(16) float As[32 * 256];
  __shared__ float Gm[32 * 68];
  __shared__ float GinvL[32 * 32];

  const int t = threadIdx.x;
  const int lane = t & 63, wv = t >> 6, quad = lane >> 4, l15 = lane & 15;
  const int T = wv & 1, kh = wv >> 1;

  for (int i = t; i < 2048; i += 256)
    ((f4v*)As)[i] = ((const f4v*)A)[i];
  __syncthreads();

  // G = A A^T (+ eps I): wave = 16x16 tile
  {
    short8 afh[2][8], afl[2][8];
    #pragma unroll
    for (int tt = 0; tt < 2; ++tt)
      #pragma unroll
      for (int s = 0; s < 8; ++s)
        split8p(As + (l15 + 16 * tt) * 256 + 32 * s + 8 * quad,
                afh[tt][s], afl[tt][s]);
    f4v cg;
    if      (wv == 0) cg = gdot8(afh[0], afl[0], afh[0], afl[0]);
    else if (wv == 1) cg = gdot8(afh[1], afl[1], afh[0], afl[0]);
    else if (wv == 2) cg = gdot8(afh[0], afl[0], afh[1], afl[1]);
    else              cg = gdot8(afh[1], afl[1], afh[1], afl[1]);
    #pragma unroll
    for (int r = 0; r < 4; ++r) {
      int gi = 16 * T + 4 * quad + r, gj = 16 * kh + l15;
      Gm[gi * 68 + gj]      = cg[r] + (gi == gj ? 1e-6f : 0.f);
      Gm[gi * 68 + 32 + gj] = (gi == gj) ? 1.f : 0.f;
    }
  }
  __syncthreads();

  // Gauss-Jordan on wave 0: lane = augmented column
  if (wv == 0) {
    float gcol[32];
    #pragma unroll
    for (int i = 0; i < 32; ++i) gcol[i] = Gm[i * 68 + lane];
    #pragma unroll
    for (int k = 0; k < 32; ++k) {
      float ckk  = __shfl(gcol[k], k);
      float ipiv = 1.f / ckk;
      float pivj = gcol[k] * ipiv;
      gcol[k] = pivj;
      #pragma unroll
      for (int i = 0; i < 32; ++i) {
        if (i == k) continue;
        float cki = __shfl(gcol[i], k);
        gcol[i] = fmaf(-cki, pivj, gcol[i]);
      }
    }
    if (lane >= 32) {
      #pragma unroll
      for (int i = 0; i < 32; ++i) GinvL[i * 32 + (lane - 32)] = gcol[i];
    }
  }
  __syncthreads();

  // KAT[n=t][m] = sum_p As[p][n] * Ginv[p][m]
  {
    float res[32];
    #pragma unroll
    for (int m = 0; m < 32; ++m) res[m] = 0.f;
    for (int p = 0; p < 32; ++p) {
      float av = As[p * 256 + t];
      #pragma unroll
      for (int m4 = 0; m4 < 8; ++m4) {
        f4v g = *(const f4v*)&GinvL[p * 32 + 4 * m4];
        res[4 * m4 + 0] = fmaf(av, g[0], res[4 * m4 + 0]);
        res[4 * m4 + 1] = fmaf(av, g[1], res[4 * m4 + 1]);
        res[4 * m4 + 2] = fmaf(av, g[2], res[4 * m4 + 2]);
        res[4 * m4 + 3] = fmaf(av, g[3], res[4 * m4 + 3]);
      }
    }
    #pragma unroll
    for (int m4 = 0; m4 < 8; ++m4) {
      f4v v = {res[4 * m4], res[4 * m4 + 1], res[4 * m4 + 2], res[4 * m4 + 3]};
      *(f4v*)&KAT[t * 32 + 4 * m4] = v;
    }
  }
}

// ---------------------------------------------------------------------------
// k_prep2: QT[n][k] = (n==k) - sum_m A[m][k]*KAT[n][m]  (= (I-P)^T rows),
// pre-split into bf16 hi/lo words. 64 blocks x 256 thr; wave = one n-row.
// ---------------------------------------------------------------------------
__global__ __launch_bounds__(256) void k_prep2(const float* __restrict__ A,
                                               const float* __restrict__ KAT,
                                               unsigned* __restrict__ QTH,
                                               unsigned* __restrict__ QTL) {
  const int t = threadIdx.x, lane = t & 63, wv = t >> 6;
  const int n = blockIdx.x * 4 + wv;
  const int k0 = lane * 4;
  const float* kr = KAT + n * 32;
  f4v p = {0.f, 0.f, 0.f, 0.f};
  #pragma unroll
  for (int m = 0; m < 32; ++m) {
    float km = kr[m];
    f4v av = *(const f4v*)&A[m * 256 + k0];
    p[0] = fmaf(km, av[0], p[0]);
    p[1] = fmaf(km, av[1], p[1]);
    p[2] = fmaf(km, av[2], p[2]);
    p[3] = fmaf(km, av[3], p[3]);
  }
  float q0 = ((k0 + 0) == n ? 1.f : 0.f) - p[0];
  float q1 = ((k0 + 1) == n ? 1.f : 0.f) - p[1];
  float q2 = ((k0 + 2) == n ? 1.f : 0.f) - p[2];
  float q3 = ((k0 + 3) == n ? 1.f : 0.f) - p[3];
  unsigned a0, b0, a1, b1;
  split_pair(q0, q1, a0, b0);
  split_pair(q2, q3, a1, b1);
  u2v hv; hv[0] = a0; hv[1] = a1;
  u2v lv; lv[0] = b0; lv[1] = b1;
  *(u2v*)&QTH[n * 128 + lane * 2] = hv;
  *(u2v*)&QTL[n * 128 + lane * 2] = lv;
}

// ---------------------------------------------------------------------------
// k_main: 256 threads (4 waves), TR=16 rows/block, grid 256.
// Fused iteration: u = z@Q + c in ONE GEMM per iteration.
//   - Q^T pre-split bf16 hi/lo fragments live in registers (4 n-tiles/wave,
//     8 k-steps, 256 VGPR) -> deliberate 1 wave/SIMD occupancy.
//   - z exchanged via double-buffered LDS fragment buffer: ONE barrier/iter.
//   - per wave per iter: 16 ds_read_b128 + 48 MFMA in 12 independent chains.
// ---------------------------------------------------------------------------
__global__ __launch_bounds__(256, 1) void k_main(
    const float* __restrict__ x,  const float* __restrict__ bmat,
    const float* __restrict__ W1, const float* __restrict__ b1,
    const float* __restrict__ W2, const float* __restrict__ b2,
    const float* __restrict__ W3, const float* __restrict__ b3,
    const float* __restrict__ KAT,
    const short* __restrict__ QTHs, const short* __restrict__ QTLs,
    const int* __restrict__ n_iter_p, float* __restrict__ out) {

  __shared__ __align__(16) float    ubuf[8768];   // MLP scratch; later y[16][260]
  __shared__ __align__(16) unsigned zfrag[8192];  // double-buffered z fragments

  const int t = threadIdx.x;
  const int lane = t & 63, wv = t >> 6, quad = lane >> 4, l15 = lane & 15;
  const int row0 = blockIdx.x * TR;

  float* xs = ubuf;            // [16][132]
  float* h1 = ubuf + 2112;     // [16][208]
  float* h2 = ubuf + 5440;     // [16][208]
  float* ys = ubuf;            // [16][260] (xs+h1 dead by then)

  for (int i = t; i < 512; i += 256) {
    int r = i >> 5, c4 = i & 31;
    *(f4v*)&xs[r * 132 + 4 * c4] = *(const f4v*)&x[(size_t)(row0 + r) * 128 + 4 * c4];
  }
  __syncthreads();

  // ---- MLP: 4 rows per wave ----
  {
    const int oc = lane;
    const bool g3 = (oc < 8);    // HID=200: col oc+192 valid iff oc<8
    const int r0 = 4 * wv;
    float acc[4][4];             // [oc-group][row]

    // L1: 128 -> 200, relu
    #pragma unroll
    for (int oi = 0; oi < 4; ++oi)
      #pragma unroll
      for (int ri = 0; ri < 4; ++ri) acc[oi][ri] = 0.f;
    for (int k4 = 0; k4 < 32; ++k4) {
      f4v xv[4];
      #pragma unroll
      for (int ri = 0; ri < 4; ++ri) xv[ri] = *(const f4v*)&xs[(r0 + ri) * 132 + 4 * k4];
      #pragma unroll
      for (int kk = 0; kk < 4; ++kk) {
        const float* wr = W1 + (4 * k4 + kk) * 200 + oc;
        float w0 = wr[0], w1c = wr[64], w2c = wr[128];
        float w3c = g3 ? wr[192] : 0.f;
        #pragma unroll
        for (int ri = 0; ri < 4; ++ri) {
          float xx = xv[ri][kk];
          acc[0][ri] = fmaf(xx, w0, acc[0][ri]);
          acc[1][ri] = fmaf(xx, w1c, acc[1][ri]);
          acc[2][ri] = fmaf(xx, w2c, acc[2][ri]);
          acc[3][ri] = fmaf(xx, w3c, acc[3][ri]);
        }
      }
    }
    #pragma unroll
    for (int oi = 0; oi < 4; ++oi) {
      if (oi == 3 && !g3) continue;
      float bb = b1[oc + 64 * oi];
      #pragma unroll
      for (int ri = 0; ri < 4; ++ri)
        h1[(r0 + ri) * 208 + oc + 64 * oi] = fmaxf(acc[oi][ri] + bb, 0.f);
    }
    __syncthreads();

    // L2: 200 -> 200, relu
    #pragma unroll
    for (int oi = 0; oi < 4; ++oi)
      #pragma unroll
      for (int ri = 0; ri < 4; ++ri) acc[oi][ri] = 0.f;
    for (int k4 = 0; k4 < 50; ++k4) {
      f4v xv[4];
      #pragma unroll
      for (int ri = 0; ri < 4; ++ri) xv[ri] = *(const f4v*)&h1[(r0 + ri) * 208 + 4 * k4];
      #pragma unroll
      for (int kk = 0; kk < 4; ++kk) {
        const float* wr = W2 + (4 * k4 + kk) * 200 + oc;
        float w0 = wr[0], w1c = wr[64], w2c = wr[128];
        float w3c = g3 ? wr[192] : 0.f;
        #pragma unroll
        for (int ri = 0; ri < 4; ++ri) {
          float xx = xv[ri][kk];
          acc[0][ri] = fmaf(xx, w0, acc[0][ri]);
          acc[1][ri] = fmaf(xx, w1c, acc[1][ri]);
          acc[2][ri] = fmaf(xx, w2c, acc[2][ri]);
          acc[3][ri] = fmaf(xx, w3c, acc[3][ri]);
        }
      }
    }
    #pragma unroll
    for (int oi = 0; oi < 4; ++oi) {
      if (oi == 3 && !g3) continue;
      float bb = b2[oc + 64 * oi];
      #pragma unroll
      for (int ri = 0; ri < 4; ++ri)
        h2[(r0 + ri) * 208 + oc + 64 * oi] = fmaxf(acc[oi][ri] + bb, 0.f);
    }
    __syncthreads();

    // L3: 200 -> 256 (no relu) -> ys
    #pragma unroll
    for (int oi = 0; oi < 4; ++oi)
      #pragma unroll
      for (int ri = 0; ri < 4; ++ri) acc[oi][ri] = 0.f;
    for (int k4 = 0; k4 < 50; ++k4) {
      f4v xv[4];
      #pragma unroll
      for (int ri = 0; ri < 4; ++ri) xv[ri] = *(const f4v*)&h2[(r0 + ri) * 208 + 4 * k4];
      #pragma unroll
      for (int kk = 0; kk < 4; ++kk) {
        const float* wr = W3 + (4 * k4 + kk) * 256 + oc;
        float w0 = wr[0], w1c = wr[64], w2c = wr[128], w3c = wr[192];
        #pragma unroll
        for (int ri = 0; ri < 4; ++ri) {
          float xx = xv[ri][kk];
          acc[0][ri] = fmaf(xx, w0, acc[0][ri]);
          acc[1][ri] = fmaf(xx, w1c, acc[1][ri]);
          acc[2][ri] = fmaf(xx, w2c, acc[2][ri]);
          acc[3][ri] = fmaf(xx, w3c, acc[3][ri]);
        }
      }
    }
    __syncthreads();   // all reads of h1/h2/xs done before ys overlays ubuf
    #pragma unroll
    for (int oi = 0; oi < 4; ++oi) {
      float bb = b3[oc + 64 * oi];
      #pragma unroll
      for (int ri = 0; ri < 4; ++ri)
        ys[(r0 + ri) * 260 + oc + 64 * oi] = acc[oi][ri] + bb;
    }
  }
  __syncthreads();

  // ---- iteration-invariant: Q^T A-operand fragments (registers, pre-split) --
  short8 qh[4][8], ql[4][8];
  #pragma unroll
  for (int u = 0; u < 4; ++u) {
    const int n = 16 * (4 * wv + u) + l15;
    #pragma unroll
    for (int s = 0; s < 8; ++s) {
      qh[u][s] = *(const short8*)&QTHs[n * 256 + 32 * s + 8 * quad];
      ql[u][s] = *(const short8*)&QTLs[n * 256 + 32 * s + 8 * quad];
    }
  }

  // ---- c = b @ KAT^T (iteration-invariant, registers) ----
  float bv[32];
  #pragma unroll
  for (int m4 = 0; m4 < 8; ++m4)
    *(f4v*)&bv[4 * m4] = *(const f4v*)&bmat[(size_t)(row0 + l15) * 32 + 4 * m4];
  f4v crv[4];
  #pragma unroll
  for (int u = 0; u < 4; ++u) {
    #pragma unroll
    for (int r = 0; r < 4; ++r) {
      const float* kp = KAT + (size_t)(16 * (4 * wv + u) + 4 * quad + r) * 32;
      float s = 0.f;
      #pragma unroll
      for (int m4 = 0; m4 < 8; ++m4) {
        f4v kv = *(const f4v*)&kp[4 * m4];
        s = fmaf(bv[4 * m4 + 0], kv[0], s);
        s = fmaf(bv[4 * m4 + 1], kv[1], s);
        s = fmaf(bv[4 * m4 + 2], kv[2], s);
        s = fmaf(bv[4 * m4 + 3], kv[3], s);
      }
      crv[u][r] = s;
    }
  }

  // ---- zfrag write offsets + z init from y; publish buffer 0 ----
  int zoff[4];
  float zr[4][4];
  #pragma unroll
  for (int u = 0; u < 4; ++u) {
    const int U = 4 * wv + u;
    const int qp = 2 * (U & 1) + (quad >> 1);
    zoff[u] = ((U >> 1) * 2) * 256 + qp * 64 + l15 * 4 + 2 * (quad & 1);
    f4v yv = *(const f4v*)&ys[l15 * 260 + 16 * U + 4 * quad];
    #pragma unroll
    for (int r = 0; r < 4; ++r) zr[u][r] = yv[r];
    pack_write(&zfrag[zoff[u]], zr[u][0], zr[u][1], zr[u][2], zr[u][3]);
  }
  __syncthreads();

  const int niter = n_iter_p[0];
  const int zrd = lane * 4;

  for (int it = 0; it <= niter; ++it) {
    const unsigned* zb = zfrag + ((it & 1) << 12);         // read buffer
    unsigned*       zw = zfrag + (((it & 1) ^ 1) << 12);   // write buffer

    // u^T = Q^T z^T + c : 12 independent accumulator chains
    f4v uA[4], uB[4], uC[4];
    #pragma unroll
    for (int u = 0; u < 4; ++u) {
      uA[u] = crv[u];
      uB[u] = (f4v){0.f, 0.f, 0.f, 0.f};
      uC[u] = (f4v){0.f, 0.f, 0.f, 0.f};
    }
    #pragma unroll
    for (int s = 0; s < 8; ++s) {
      short8 zh = *(const short8*)&zb[(2 * s + 0) * 256 + zrd];
      short8 zl = *(const short8*)&zb[(2 * s + 1) * 256 + zrd];
      #pragma unroll
      for (int u = 0; u < 4; ++u) uA[u] = mfma16(qh[u][s], zh, uA[u]);
      #pragma unroll
      for (int u = 0; u < 4; ++u) uB[u] = mfma16(ql[u][s], zh, uB[u]);
      #pragma unroll
      for (int u = 0; u < 4; ++u) uC[u] = mfma16(qh[u][s], zl, uC[u]);
    }

    if (it < niter) {
      #pragma unroll
      for (int u = 0; u < 4; ++u) {
        float zn[4];
        #pragma unroll
        for (int r = 0; r < 4; ++r) {
          float uv = (uA[u][r] + uB[u][r]) + uC[u][r];
          float z  = zr[u][r];
          float vv = fminf(fmaxf(fmaf(2.f, uv, -z), 0.f), 1.f);  // clip(2u - z)
          zn[r] = fmaf(1.7f, vv - uv, z);                        // z += 1.7*(v-u)
          zr[u][r] = zn[r];
        }
        pack_write(&zw[zoff[u]], zn[0], zn[1], zn[2], zn[3]);
      }
      __syncthreads();
    } else {
      #pragma unroll
      for (int u = 0; u < 4; ++u) {
        const int U = 4 * wv + u;
        f4v ov;
        #pragma unroll
        for (int r = 0; r < 4; ++r) ov[r] = (uA[u][r] + uB[u][r]) + uC[u][r];
        *(f4v*)&out[(size_t)(row0 + l15) * 256 + 16 * U + 4 * quad] = ov;
      }
    }
  }
}

// ---------------------------------------------------------------------------
extern "C" void kernel_launch(void* const* d_in, const int* in_sizes, int n_in,
                              void* d_out, int out_size, void* d_ws, size_t ws_size,
                              hipStream_t stream) {
  const float* x    = (const float*)d_in[0];
  const float* bmat = (const float*)d_in[1];
  const float* W1   = (const float*)d_in[2];
  const float* b1   = (const float*)d_in[3];
  const float* W2   = (const float*)d_in[4];
  const float* b2   = (const float*)d_in[5];
  const float* W3   = (const float*)d_in[6];
  const float* b3   = (const float*)d_in[7];
  const float* A    = (const float*)d_in[8];
  const int*  n_it  = (const int*)d_in[10];

  float*    KAT = (float*)d_ws;                       // 256*32 f32   = 32 KB
  unsigned* QTH = (unsigned*)((char*)d_ws + 32768);   // 256*256 bf16 = 128 KB
  unsigned* QTL = QTH + 256 * 128;                    // 256*256 bf16 = 128 KB
  float* out = (float*)d_out;

  hipLaunchKernelGGL(k_prep,  dim3(1),       dim3(256), 0, stream, A, KAT);
  hipLaunchKernelGGL(k_prep2, dim3(64),      dim3(256), 0, stream, A, KAT, QTH, QTL);
  hipLaunchKernelGGL(k_main,  dim3(Bn / TR), dim3(256), 0, stream,
                     x, bmat, W1, b1, W2, b2, W3, b3, KAT,
                     (const short*)QTH, (const short*)QTL, n_it, out);
}

// Round 2
// 262.117 us; speedup vs baseline: 1.1234x; 1.1234x over previous
//
#include <hip/hip_runtime.h>
#include <hip/hip_bf16.h>

typedef float    f4v    __attribute__((ext_vector_type(4)));
typedef short    short8 __attribute__((ext_vector_type(8)));
typedef unsigned u2v    __attribute__((ext_vector_type(2)));

constexpr int Bn = 4096, TR = 16;

// ---- split-bf16 helpers ----------------------------------------------------
__device__ inline unsigned cvt2(float x, float y) {
  union { __hip_bfloat162 h; unsigned u; } c;
  c.h = __float22bfloat162_rn(float2{x, y});
  return c.u;   // low16 = bf16(x), high16 = bf16(y)
}
__device__ inline void split_pair(float x, float y, unsigned& hp, unsigned& lp) {
  hp = cvt2(x, y);
  float hx = __uint_as_float(hp << 16);
  float hy = __uint_as_float(hp & 0xffff0000u);
  lp = cvt2(x - hx, y - hy);
}
union S8U { unsigned u[4]; short8 s; };
__device__ inline void split8(const float v[8], short8& hi, short8& lo) {
  S8U h, l;
  #pragma unroll
  for (int d = 0; d < 4; ++d) split_pair(v[2 * d], v[2 * d + 1], h.u[d], l.u[d]);
  hi = h.s; lo = l.s;
}
__device__ inline void split8p(const float* p, short8& hi, short8& lo) {
  f4v a = *(const f4v*)p, b = *(const f4v*)(p + 4);
  float v[8] = {a[0], a[1], a[2], a[3], b[0], b[1], b[2], b[3]};
  split8(v, hi, lo);
}
__device__ inline f4v mfma16(short8 a, short8 b, f4v c) {
  return __builtin_amdgcn_mfma_f32_16x16x32_bf16(a, b, c, 0, 0, 0);
}
__device__ __attribute__((always_inline)) inline f4v gdot8(
    const short8 (&ah)[8], const short8 (&al)[8],
    const short8 (&bh)[8], const short8 (&bl)[8]) {
  f4v c = {0.f, 0.f, 0.f, 0.f};
  #pragma unroll
  for (int s = 0; s < 8; ++s) {
    c = mfma16(ah[s], bh[s], c);
    c = mfma16(al[s], bh[s], c);
    c = mfma16(ah[s], bl[s], c);
  }
  return c;
}

// pack 4 fp32 -> bf16 hi/lo fragment words, write hi at dst[0..1], lo at dst[256..257]
__device__ inline void pack_write(unsigned* dst, float z0, float z1, float z2, float z3) {
  unsigned a0, b0, a1, b1;
  split_pair(z0, z1, a0, b0);
  split_pair(z2, z3, a1, b1);
  u2v hv; hv[0] = a0; hv[1] = a1;
  u2v lv; lv[0] = b0; lv[1] = b1;
  *(u2v*)&dst[0]   = hv;
  *(u2v*)&dst[256] = lv;
}

// ---------------------------------------------------------------------------
// k_prep: KAT[n][m] = (inv(A A^T + 1e-6 I) @ A)^T -> ws. 1 block, 256 thr.
// ---------------------------------------------------------------------------
__global__ __launch_bounds__(256) void k_prep(const float* __restrict__ A,
                                              float* __restrict__ KAT) {
  __shared__ __align__(16) float As[32 * 256];
  __shared__ float Gm[32 * 68];
  __shared__ float GinvL[32 * 32];

  const int t = threadIdx.x;
  const int lane = t & 63, wv = t >> 6, quad = lane >> 4, l15 = lane & 15;
  const int T = wv & 1, kh = wv >> 1;

  for (int i = t; i < 2048; i += 256)
    ((f4v*)As)[i] = ((const f4v*)A)[i];
  __syncthreads();

  // G = A A^T (+ eps I): wave = 16x16 tile
  {
    short8 afh[2][8], afl[2][8];
    #pragma unroll
    for (int tt = 0; tt < 2; ++tt)
      #pragma unroll
      for (int s = 0; s < 8; ++s)
        split8p(As + (l15 + 16 * tt) * 256 + 32 * s + 8 * quad,
                afh[tt][s], afl[tt][s]);
    f4v cg;
    if      (wv == 0) cg = gdot8(afh[0], afl[0], afh[0], afl[0]);
    else if (wv == 1) cg = gdot8(afh[1], afl[1], afh[0], afl[0]);
    else if (wv == 2) cg = gdot8(afh[0], afl[0], afh[1], afl[1]);
    else              cg = gdot8(afh[1], afl[1], afh[1], afl[1]);
    #pragma unroll
    for (int r = 0; r < 4; ++r) {
      int gi = 16 * T + 4 * quad + r, gj = 16 * kh + l15;
      Gm[gi * 68 + gj]      = cg[r] + (gi == gj ? 1e-6f : 0.f);
      Gm[gi * 68 + 32 + gj] = (gi == gj) ? 1.f : 0.f;
    }
  }
  __syncthreads();

  // Gauss-Jordan on wave 0: lane = augmented column
  if (wv == 0) {
    float gcol[32];
    #pragma unroll
    for (int i = 0; i < 32; ++i) gcol[i] = Gm[i * 68 + lane];
    #pragma unroll
    for (int k = 0; k < 32; ++k) {
      float ckk  = __shfl(gcol[k], k);
      float ipiv = 1.f / ckk;
      float pivj = gcol[k] * ipiv;
      gcol[k] = pivj;
      #pragma unroll
      for (int i = 0; i < 32; ++i) {
        if (i == k) continue;
        float cki = __shfl(gcol[i], k);
        gcol[i] = fmaf(-cki, pivj, gcol[i]);
      }
    }
    if (lane >= 32) {
      #pragma unroll
      for (int i = 0; i < 32; ++i) GinvL[i * 32 + (lane - 32)] = gcol[i];
    }
  }
  __syncthreads();

  // KAT[n=t][m] = sum_p As[p][n] * Ginv[p][m]
  {
    float res[32];
    #pragma unroll
    for (int m = 0; m < 32; ++m) res[m] = 0.f;
    for (int p = 0; p < 32; ++p) {
      float av = As[p * 256 + t];
      #pragma unroll
      for (int m4 = 0; m4 < 8; ++m4) {
        f4v g = *(const f4v*)&GinvL[p * 32 + 4 * m4];
        res[4 * m4 + 0] = fmaf(av, g[0], res[4 * m4 + 0]);
        res[4 * m4 + 1] = fmaf(av, g[1], res[4 * m4 + 1]);
        res[4 * m4 + 2] = fmaf(av, g[2], res[4 * m4 + 2]);
        res[4 * m4 + 3] = fmaf(av, g[3], res[4 * m4 + 3]);
      }
    }
    #pragma unroll
    for (int m4 = 0; m4 < 8; ++m4) {
      f4v v = {res[4 * m4], res[4 * m4 + 1], res[4 * m4 + 2], res[4 * m4 + 3]};
      *(f4v*)&KAT[t * 32 + 4 * m4] = v;
    }
  }
}

// ---------------------------------------------------------------------------
// k_prep2: QT[n][k] = (n==k) - sum_m A[m][k]*KAT[n][m]  (= (I-P)^T rows),
// pre-split into bf16 hi/lo words. 64 blocks x 256 thr; wave = one n-row.
// ---------------------------------------------------------------------------
__global__ __launch_bounds__(256) void k_prep2(const float* __restrict__ A,
                                               const float* __restrict__ KAT,
                                               unsigned* __restrict__ QTH,
                                               unsigned* __restrict__ QTL) {
  const int t = threadIdx.x, lane = t & 63, wv = t >> 6;
  const int n = blockIdx.x * 4 + wv;
  const int k0 = lane * 4;
  const float* kr = KAT + n * 32;
  f4v p = {0.f, 0.f, 0.f, 0.f};
  #pragma unroll
  for (int m = 0; m < 32; ++m) {
    float km = kr[m];
    f4v av = *(const f4v*)&A[m * 256 + k0];
    p[0] = fmaf(km, av[0], p[0]);
    p[1] = fmaf(km, av[1], p[1]);
    p[2] = fmaf(km, av[2], p[2]);
    p[3] = fmaf(km, av[3], p[3]);
  }
  float q0 = ((k0 + 0) == n ? 1.f : 0.f) - p[0];
  float q1 = ((k0 + 1) == n ? 1.f : 0.f) - p[1];
  float q2 = ((k0 + 2) == n ? 1.f : 0.f) - p[2];
  float q3 = ((k0 + 3) == n ? 1.f : 0.f) - p[3];
  unsigned a0, b0, a1, b1;
  split_pair(q0, q1, a0, b0);
  split_pair(q2, q3, a1, b1);
  u2v hv; hv[0] = a0; hv[1] = a1;
  u2v lv; lv[0] = b0; lv[1] = b1;
  *(u2v*)&QTH[n * 128 + lane * 2] = hv;
  *(u2v*)&QTL[n * 128 + lane * 2] = lv;
}

// ---------------------------------------------------------------------------
// k_main: 512 threads (8 waves), TR=16 rows/block, grid 256.
// Fused iteration: u = z@Q + c in ONE GEMM per iteration.
//   - Q^T fragments: 2 n-tiles per wave -> 32 short8 = 128 VGPR (NO spill;
//     round-1's 4-tiles/wave needed 256+ VGPR and spilled at VGPR_Count=204).
//   - 2 waves/SIMD hide LDS/barrier latency.
//   - z exchanged via double-buffered LDS fragments: ONE barrier/iter.
//   - per wave per iter: 16 ds_read_b128 + 24 MFMA in 6 independent chains.
// ---------------------------------------------------------------------------
__global__ __launch_bounds__(512, 2) void k_main(
    const float* __restrict__ x,  const float* __restrict__ bmat,
    const float* __restrict__ W1, const float* __restrict__ b1,
    const float* __restrict__ W2, const float* __restrict__ b2,
    const float* __restrict__ W3, const float* __restrict__ b3,
    const float* __restrict__ KAT,
    const short* __restrict__ QTHs, const short* __restrict__ QTLs,
    const int* __restrict__ n_iter_p, float* __restrict__ out) {

  __shared__ __align__(16) float    ubuf[8768];   // MLP scratch; later y[16][260]
  __shared__ __align__(16) unsigned zfrag[8192];  // double-buffered z fragments

  const int t = threadIdx.x;
  const int lane = t & 63, wv = t >> 6, quad = lane >> 4, l15 = lane & 15;
  const int row0 = blockIdx.x * TR;

  float* xs = ubuf;            // [16][132]
  float* h1 = ubuf + 2112;     // [16][208]
  float* h2 = ubuf + 5440;     // [16][208]
  float* ys = ubuf;            // [16][260] (xs+h1 dead by then)

  if (t < 512) {
    int r = t >> 5, c4 = t & 31;
    *(f4v*)&xs[r * 132 + 4 * c4] = *(const f4v*)&x[(size_t)(row0 + r) * 128 + 4 * c4];
  }
  __syncthreads();

  // ---- MLP: 2 rows per wave (proven 512-thread version) ----
  {
    const int rg = wv, oc = lane;
    const bool g3 = (oc < 8);    // HID=200: col oc+192 valid iff oc<8
    float acc[4][2];

    // L1: 128 -> 200, relu
    #pragma unroll
    for (int oi = 0; oi < 4; ++oi) { acc[oi][0] = 0.f; acc[oi][1] = 0.f; }
    for (int k4 = 0; k4 < 32; ++k4) {
      f4v xv0 = *(const f4v*)&xs[(2 * rg + 0) * 132 + 4 * k4];
      f4v xv1 = *(const f4v*)&xs[(2 * rg + 1) * 132 + 4 * k4];
      #pragma unroll
      for (int kk = 0; kk < 4; ++kk) {
        const float* wr = W1 + (4 * k4 + kk) * 200 + oc;
        float w0 = wr[0], w1c = wr[64], w2c = wr[128];
        float w3c = g3 ? wr[192] : 0.f;
        acc[0][0] = fmaf(xv0[kk], w0, acc[0][0]);  acc[0][1] = fmaf(xv1[kk], w0, acc[0][1]);
        acc[1][0] = fmaf(xv0[kk], w1c, acc[1][0]); acc[1][1] = fmaf(xv1[kk], w1c, acc[1][1]);
        acc[2][0] = fmaf(xv0[kk], w2c, acc[2][0]); acc[2][1] = fmaf(xv1[kk], w2c, acc[2][1]);
        acc[3][0] = fmaf(xv0[kk], w3c, acc[3][0]); acc[3][1] = fmaf(xv1[kk], w3c, acc[3][1]);
      }
    }
    #pragma unroll
    for (int oi = 0; oi < 4; ++oi) {
      if (oi == 3 && !g3) continue;
      float bb = b1[oc + 64 * oi];
      h1[(2 * rg + 0) * 208 + oc + 64 * oi] = fmaxf(acc[oi][0] + bb, 0.f);
      h1[(2 * rg + 1) * 208 + oc + 64 * oi] = fmaxf(acc[oi][1] + bb, 0.f);
    }
    __syncthreads();

    // L2: 200 -> 200, relu
    #pragma unroll
    for (int oi = 0; oi < 4; ++oi) { acc[oi][0] = 0.f; acc[oi][1] = 0.f; }
    for (int k4 = 0; k4 < 50; ++k4) {
      f4v xv0 = *(const f4v*)&h1[(2 * rg + 0) * 208 + 4 * k4];
      f4v xv1 = *(const f4v*)&h1[(2 * rg + 1) * 208 + 4 * k4];
      #pragma unroll
      for (int kk = 0; kk < 4; ++kk) {
        const float* wr = W2 + (4 * k4 + kk) * 200 + oc;
        float w0 = wr[0], w1c = wr[64], w2c = wr[128];
        float w3c = g3 ? wr[192] : 0.f;
        acc[0][0] = fmaf(xv0[kk], w0, acc[0][0]);  acc[0][1] = fmaf(xv1[kk], w0, acc[0][1]);
        acc[1][0] = fmaf(xv0[kk], w1c, acc[1][0]); acc[1][1] = fmaf(xv1[kk], w1c, acc[1][1]);
        acc[2][0] = fmaf(xv0[kk], w2c, acc[2][0]); acc[2][1] = fmaf(xv1[kk], w2c, acc[2][1]);
        acc[3][0] = fmaf(xv0[kk], w3c, acc[3][0]); acc[3][1] = fmaf(xv1[kk], w3c, acc[3][1]);
      }
    }
    #pragma unroll
    for (int oi = 0; oi < 4; ++oi) {
      if (oi == 3 && !g3) continue;
      float bb = b2[oc + 64 * oi];
      h2[(2 * rg + 0) * 208 + oc + 64 * oi] = fmaxf(acc[oi][0] + bb, 0.f);
      h2[(2 * rg + 1) * 208 + oc + 64 * oi] = fmaxf(acc[oi][1] + bb, 0.f);
    }
    __syncthreads();

    // L3: 200 -> 256 (no relu) -> ys
    #pragma unroll
    for (int oi = 0; oi < 4; ++oi) { acc[oi][0] = 0.f; acc[oi][1] = 0.f; }
    for (int k4 = 0; k4 < 50; ++k4) {
      f4v xv0 = *(const f4v*)&h2[(2 * rg + 0) * 208 + 4 * k4];
      f4v xv1 = *(const f4v*)&h2[(2 * rg + 1) * 208 + 4 * k4];
      #pragma unroll
      for (int kk = 0; kk < 4; ++kk) {
        const float* wr = W3 + (4 * k4 + kk) * 256 + oc;
        float w0 = wr[0], w1c = wr[64], w2c = wr[128], w3c = wr[192];
        acc[0][0] = fmaf(xv0[kk], w0, acc[0][0]);  acc[0][1] = fmaf(xv1[kk], w0, acc[0][1]);
        acc[1][0] = fmaf(xv0[kk], w1c, acc[1][0]); acc[1][1] = fmaf(xv1[kk], w1c, acc[1][1]);
        acc[2][0] = fmaf(xv0[kk], w2c, acc[2][0]); acc[2][1] = fmaf(xv1[kk], w2c, acc[2][1]);
        acc[3][0] = fmaf(xv0[kk], w3c, acc[3][0]); acc[3][1] = fmaf(xv1[kk], w3c, acc[3][1]);
      }
    }
    __syncthreads();   // reads of h2/xs done before ys overlays ubuf
    #pragma unroll
    for (int oi = 0; oi < 4; ++oi) {
      float bb = b3[oc + 64 * oi];
      ys[(2 * rg + 0) * 260 + oc + 64 * oi] = acc[oi][0] + bb;
      ys[(2 * rg + 1) * 260 + oc + 64 * oi] = acc[oi][1] + bb;
    }
  }
  __syncthreads();

  // ---- iteration-invariant: Q^T A-operand fragments (registers, pre-split) --
  // 2 n-tiles per wave: 32 short8 = 128 VGPR, fits without spilling.
  short8 qh[2][8], ql[2][8];
  #pragma unroll
  for (int u = 0; u < 2; ++u) {
    const int n = 16 * (2 * wv + u) + l15;
    #pragma unroll
    for (int s = 0; s < 8; ++s) {
      qh[u][s] = *(const short8*)&QTHs[n * 256 + 32 * s + 8 * quad];
      ql[u][s] = *(const short8*)&QTLs[n * 256 + 32 * s + 8 * quad];
    }
  }

  // ---- c = b @ KAT^T (iteration-invariant, registers) ----
  float bv[32];
  #pragma unroll
  for (int m4 = 0; m4 < 8; ++m4)
    *(f4v*)&bv[4 * m4] = *(const f4v*)&bmat[(size_t)(row0 + l15) * 32 + 4 * m4];
  f4v crv[2];
  #pragma unroll
  for (int u = 0; u < 2; ++u) {
    #pragma unroll
    for (int r = 0; r < 4; ++r) {
      const float* kp = KAT + (size_t)(16 * (2 * wv + u) + 4 * quad + r) * 32;
      float s = 0.f;
      #pragma unroll
      for (int m4 = 0; m4 < 8; ++m4) {
        f4v kv = *(const f4v*)&kp[4 * m4];
        s = fmaf(bv[4 * m4 + 0], kv[0], s);
        s = fmaf(bv[4 * m4 + 1], kv[1], s);
        s = fmaf(bv[4 * m4 + 2], kv[2], s);
        s = fmaf(bv[4 * m4 + 3], kv[3], s);
      }
      crv[u][r] = s;
    }
  }

  // ---- zfrag write offsets + z init from y; publish buffer 0 ----
  int zoff[2];
  float zr[2][4];
  #pragma unroll
  for (int u = 0; u < 2; ++u) {
    const int U = 2 * wv + u;
    const int qp = 2 * (U & 1) + (quad >> 1);
    zoff[u] = ((U >> 1) * 2) * 256 + qp * 64 + l15 * 4 + 2 * (quad & 1);
    f4v yv = *(const f4v*)&ys[l15 * 260 + 16 * U + 4 * quad];
    #pragma unroll
    for (int r = 0; r < 4; ++r) zr[u][r] = yv[r];
    pack_write(&zfrag[zoff[u]], zr[u][0], zr[u][1], zr[u][2], zr[u][3]);
  }
  __syncthreads();

  const int niter = n_iter_p[0];
  const int zrd = lane * 4;

  for (int it = 0; it <= niter; ++it) {
    const unsigned* zb = zfrag + ((it & 1) << 12);         // read buffer
    unsigned*       zw = zfrag + (((it & 1) ^ 1) << 12);   // write buffer

    // u^T = Q^T z^T + c : 6 independent accumulator chains
    f4v uA[2], uB[2], uC[2];
    #pragma unroll
    for (int u = 0; u < 2; ++u) {
      uA[u] = crv[u];
      uB[u] = (f4v){0.f, 0.f, 0.f, 0.f};
      uC[u] = (f4v){0.f, 0.f, 0.f, 0.f};
    }
    #pragma unroll
    for (int s = 0; s < 8; ++s) {
      short8 zh = *(const short8*)&zb[(2 * s + 0) * 256 + zrd];
      short8 zl = *(const short8*)&zb[(2 * s + 1) * 256 + zrd];
      #pragma unroll
      for (int u = 0; u < 2; ++u) uA[u] = mfma16(qh[u][s], zh, uA[u]);
      #pragma unroll
      for (int u = 0; u < 2; ++u) uB[u] = mfma16(ql[u][s], zh, uB[u]);
      #pragma unroll
      for (int u = 0; u < 2; ++u) uC[u] = mfma16(qh[u][s], zl, uC[u]);
    }

    if (it < niter) {
      #pragma unroll
      for (int u = 0; u < 2; ++u) {
        float zn[4];
        #pragma unroll
        for (int r = 0; r < 4; ++r) {
          float uv = (uA[u][r] + uB[u][r]) + uC[u][r];
          float z  = zr[u][r];
          float vv = fminf(fmaxf(fmaf(2.f, uv, -z), 0.f), 1.f);  // clip(2u - z)
          zn[r] = fmaf(1.7f, vv - uv, z);                        // z += 1.7*(v-u)
          zr[u][r] = zn[r];
        }
        pack_write(&zw[zoff[u]], zn[0], zn[1], zn[2], zn[3]);
      }
      __syncthreads();
    } else {
      #pragma unroll
      for (int u = 0; u < 2; ++u) {
        const int U = 2 * wv + u;
        f4v ov;
        #pragma unroll
        for (int r = 0; r < 4; ++r) ov[r] = (uA[u][r] + uB[u][r]) + uC[u][r];
        *(f4v*)&out[(size_t)(row0 + l15) * 256 + 16 * U + 4 * quad] = ov;
      }
    }
  }
}

// ---------------------------------------------------------------------------
extern "C" void kernel_launch(void* const* d_in, const int* in_sizes, int n_in,
                              void* d_out, int out_size, void* d_ws, size_t ws_size,
                              hipStream_t stream) {
  const float* x    = (const float*)d_in[0];
  const float* bmat = (const float*)d_in[1];
  const float* W1   = (const float*)d_in[2];
  const float* b1   = (const float*)d_in[3];
  const float* W2   = (const float*)d_in[4];
  const float* b2   = (const float*)d_in[5];
  const float* W3   = (const float*)d_in[6];
  const float* b3   = (const float*)d_in[7];
  const float* A    = (const float*)d_in[8];
  const int*  n_it  = (const int*)d_in[10];

  float*    KAT = (float*)d_ws;                       // 256*32 f32   = 32 KB
  unsigned* QTH = (unsigned*)((char*)d_ws + 32768);   // 256*256 bf16 = 128 KB
  unsigned* QTL = QTH + 256 * 128;                    // 256*256 bf16 = 128 KB
  float* out = (float*)d_out;

  hipLaunchKernelGGL(k_prep,  dim3(1),       dim3(256), 0, stream, A, KAT);
  hipLaunchKernelGGL(k_prep2, dim3(64),      dim3(256), 0, stream, A, KAT, QTH, QTL);
  hipLaunchKernelGGL(k_main,  dim3(Bn / TR), dim3(512), 0, stream,
                     x, bmat, W1, b1, W2, b2, W3, b3, KAT,
                     (const short*)QTH, (const short*)QTL, n_it, out);
}